// Round 2
// baseline (12932.410 us; speedup 1.0000x reference)
//
#include <hip/hip_runtime.h>
#include <math.h>

constexpr int H    = 500;
constexpr int H3   = 1500;
constexpr int SEQ  = 256;
constexpr int V    = 50257;
constexpr int TDEC = 64;
constexpr int NLB  = (V + 63) / 64;   // logits blocks: 64 rows per block
constexpr int SB   = 50;              // scan blocks per direction
constexpr int UPB  = 10;              // hidden units per scan block

__device__ __forceinline__ float sigmoidf_(float x) { return 1.f / (1.f + expf(-x)); }

__device__ __forceinline__ float wred(float v) {
  #pragma unroll
  for (int off = 32; off > 0; off >>= 1) v += __shfl_down(v, off, 64);
  return v;
}

// ---------------- software grid barrier (device scope) ----------------
__device__ __forceinline__ void gbar(int* cnt, int* gen, int nblk) {
  __syncthreads();
  if (threadIdx.x == 0) {
    __threadfence();
    int g = __hip_atomic_load(gen, __ATOMIC_SEQ_CST, __HIP_MEMORY_SCOPE_AGENT);
    int prev = __hip_atomic_fetch_add(cnt, 1, __ATOMIC_SEQ_CST, __HIP_MEMORY_SCOPE_AGENT);
    if (prev == nblk - 1) {
      __hip_atomic_store(cnt, 0, __ATOMIC_SEQ_CST, __HIP_MEMORY_SCOPE_AGENT);
      __hip_atomic_fetch_add(gen, 1, __ATOMIC_SEQ_CST, __HIP_MEMORY_SCOPE_AGENT);
    } else {
      while (__hip_atomic_load(gen, __ATOMIC_SEQ_CST, __HIP_MEMORY_SCOPE_AGENT) == g)
        __builtin_amdgcn_s_sleep(2);
    }
    __threadfence();
  }
  __syncthreads();
}

// ---------------- init: tok = SOS ----------------
__global__ void init_k(int* tok) {
  if (threadIdx.x == 0) tok[0] = 1;  // SOS
}

// ---------------- embedding lookup: ex[t] = emb[seq[t]] ----------------
__global__ void embed_k(const int* __restrict__ seq, const float* __restrict__ emb,
                        float* __restrict__ ex) {
  int t = blockIdx.x;
  int tok = seq[t];
  for (int i = threadIdx.x; i < H; i += blockDim.x)
    ex[(size_t)t * H + i] = emb[(size_t)tok * H + i];
}

// ---------------- C[m][n] = bias[n] + sum_k X[m*K+k] * W[n*K+k] ----------------
__global__ __launch_bounds__(256) void gemm_nt(const float* __restrict__ X,
                                               const float* __restrict__ W,
                                               const float* __restrict__ bias,
                                               float* __restrict__ C,
                                               int M, int N, int K) {
  __shared__ float Xs[64][17];
  __shared__ float Ws[64][17];
  int bm = blockIdx.y * 64, bn = blockIdx.x * 64;
  int tid = threadIdx.x;
  int tx = tid % 16, ty = tid / 16;
  float acc[4][4] = {};
  for (int k0 = 0; k0 < K; k0 += 16) {
    for (int i = tid; i < 64 * 16; i += 256) {
      int m = i / 16, k = i % 16;
      int gm = bm + m, gk = k0 + k, gn = bn + m;
      Xs[m][k] = (gm < M && gk < K) ? X[(size_t)gm * K + gk] : 0.f;
      Ws[m][k] = (gn < N && gk < K) ? W[(size_t)gn * K + gk] : 0.f;
    }
    __syncthreads();
    #pragma unroll
    for (int k = 0; k < 16; ++k) {
      float xv[4], wv[4];
      #pragma unroll
      for (int i = 0; i < 4; ++i) xv[i] = Xs[ty * 4 + i][k];
      #pragma unroll
      for (int j = 0; j < 4; ++j) wv[j] = Ws[tx * 4 + j][k];
      #pragma unroll
      for (int i = 0; i < 4; ++i)
        #pragma unroll
        for (int j = 0; j < 4; ++j) acc[i][j] += xv[i] * wv[j];
    }
    __syncthreads();
  }
  for (int i = 0; i < 4; ++i) {
    int gm = bm + ty * 4 + i;
    if (gm >= M) continue;
    for (int j = 0; j < 4; ++j) {
      int gn = bn + tx * 4 + j;
      if (gn >= N) continue;
      C[(size_t)gm * N + gn] = acc[i][j] + bias[gn];
    }
  }
}

// ---------------- persistent GRU scan: one launch per layer, fwd+bwd ----------------
// grid = 100 blocks (50 per direction), block = 512 threads.
// Each block owns UPB hidden units; its 3*UPB Whh rows live in LDS (60 KB).
// h ping-pongs between two global buffers per direction; one grid barrier per step.
__global__ __launch_bounds__(512, 1) void gru_scan_persist(
    const float* __restrict__ gxF, const float* __restrict__ gxB,
    const float* __restrict__ WhhF, const float* __restrict__ WhhB,
    const float* __restrict__ bhhF, const float* __restrict__ bhhB,
    float* __restrict__ hFA, float* __restrict__ hFB,
    float* __restrict__ hBA, float* __restrict__ hBB,
    float* __restrict__ yF, float* __restrict__ yB, int ystride,
    int* bcnt, int* bgen) {
  __shared__ float w_lds[30 * 500];   // 60 KB
  __shared__ float gates[32];
  int dir = blockIdx.x / SB;
  int bu  = blockIdx.x % SB;
  int u0  = bu * UPB;
  const float* gx  = dir ? gxB : gxF;
  const float* Whh = dir ? WhhB : WhhF;
  const float* bhh = dir ? bhhB : bhhF;
  float* hA = dir ? hBA : hFA;
  float* hB = dir ? hBB : hFB;
  float* y  = dir ? yB : yF;
  int tid = threadIdx.x, lane = tid & 63, wid = tid >> 6;

  // stage this block's Whh rows into LDS (rows: gate g in {r,z,n} x local unit lu)
  for (int idx = tid; idx < 30 * 500; idx += 512) {
    int r = idx / 500, k = idx - r * 500;
    int g = r / UPB, lu = r - g * UPB;
    w_lds[idx] = Whh[(size_t)(g * 500 + u0 + lu) * 500 + k];
  }
  __syncthreads();

  float hreg[8];
  for (int t = 0; t < SEQ; ++t) {
    const float* hin  = (t & 1) ? hB : hA;
    float*       hout = (t & 1) ? hA : hB;
    int teff = dir ? (SEQ - 1 - t) : t;
    #pragma unroll
    for (int j = 0; j < 8; ++j) {
      int k = lane + 64 * j;
      hreg[j] = (t > 0 && k < 500) ? hin[k] : 0.f;
    }
    for (int r = wid; r < 30; r += 8) {
      const float* wr = &w_lds[r * 500];
      float acc = 0.f;
      #pragma unroll
      for (int j = 0; j < 8; ++j) {
        int k = lane + 64 * j;
        if (k < 500) acc += wr[k] * hreg[j];
      }
      acc = wred(acc);
      if (lane == 0) gates[r] = acc;
    }
    __syncthreads();
    if (tid < UPB) {
      int u = u0 + tid;
      float hold = (t > 0) ? hin[u] : 0.f;
      const float* g = gx + (size_t)teff * H3;
      float rr = sigmoidf_(g[u]        + gates[tid]           + bhh[u]);
      float zz = sigmoidf_(g[500 + u]  + gates[UPB + tid]     + bhh[500 + u]);
      float nn = tanhf(    g[1000 + u] + rr * (gates[2 * UPB + tid] + bhh[1000 + u]));
      float hp = (1.f - zz) * nn + zz * hold;
      hout[u] = hp;
      y[(size_t)teff * ystride + u] = hp;
    }
    if (t < SEQ - 1) gbar(bcnt, bgen, 2 * SB);
  }
}

// ---------------- enc_out = y1f + y1b ----------------
__global__ void add_k(const float* __restrict__ a, const float* __restrict__ b,
                      float* __restrict__ c, int n) {
  int i = blockIdx.x * blockDim.x + threadIdx.x;
  if (i < n) c[i] = a[i] + b[i];
}

// ---------------- fused decoder step (cells + attention + concat) ----------------
__device__ __forceinline__ void cell_phase(int blk, int wid, int lane, int tid,
    const float* x_lds, const float* h_lds, float* gates,
    const float* Wih, const float* Whh, const float* bih, const float* bhh,
    float* hout) {
  for (int rr = wid; rr < 96; rr += 16) {
    int lu = rr & 15, kind = rr >> 4;
    int u = blk * 16 + lu;
    if (u < 500) {
      const float* row = (kind < 3) ? (Wih + (size_t)(kind * 500 + u) * 500)
                                    : (Whh + (size_t)((kind - 3) * 500 + u) * 500);
      const float* vec = (kind < 3) ? x_lds : h_lds;
      float acc = 0.f;
      #pragma unroll
      for (int j = 0; j < 8; ++j) {
        int k = lane + 64 * j;
        if (k < 500) acc += row[k] * vec[k];
      }
      acc = wred(acc);
      if (lane == 0) gates[rr] = acc;
    }
  }
  __syncthreads();
  if (tid < 16) {
    int u = blk * 16 + tid;
    if (u < 500) {
      float sxr = gates[tid],      sxz = gates[16 + tid], sxn = gates[32 + tid];
      float shr = gates[48 + tid], shz = gates[64 + tid], shn = gates[80 + tid];
      float r = sigmoidf_(sxr + bih[u]        + shr + bhh[u]);
      float z = sigmoidf_(sxz + bih[500 + u]  + shz + bhh[500 + u]);
      float n = tanhf(    sxn + bih[1000 + u] + r * (shn + bhh[1000 + u]));
      hout[u] = (1.f - z) * n + z * h_lds[u];
    }
  }
}

__global__ __launch_bounds__(1024, 1) void dec_step_fused(
    const int* __restrict__ tok, const float* __restrict__ emb,
    const float* __restrict__ h0in, float* __restrict__ h0out,
    const float* __restrict__ h1in, float* __restrict__ h1out,
    const float* __restrict__ dWih, const float* __restrict__ dWhh,
    const float* __restrict__ dbih, const float* __restrict__ dbhh,
    const float* __restrict__ enc_out, const float* __restrict__ cW,
    const float* __restrict__ cb,
    float* __restrict__ scores, float* __restrict__ ctx, float* __restrict__ cvec,
    int* bcnt, int* bgen) {
  __shared__ float x_lds[512], h_lds[512], gates[96], red[256], sc_lds[256];
  int tid = threadIdx.x, lane = tid & 63, wid = tid >> 6, blk = blockIdx.x;

  // ---- phase A: layer-0 GRU cell (x = emb[tok]) ----
  int tk = tok[0];
  for (int i = tid; i < 500; i += 1024) {
    x_lds[i] = emb[(size_t)tk * 500 + i];
    h_lds[i] = h0in[i];
  }
  __syncthreads();
  cell_phase(blk, wid, lane, tid, x_lds, h_lds, gates, dWih, dWhh, dbih, dbhh, h0out);
  gbar(bcnt, bgen, 32);

  // ---- phase B: layer-1 GRU cell (x = h0out) ----
  for (int i = tid; i < 500; i += 1024) {
    x_lds[i] = h0out[i];
    h_lds[i] = h1in[i];
  }
  __syncthreads();
  cell_phase(blk, wid, lane, tid, x_lds, h_lds, gates,
             dWih + 750000, dWhh + 750000, dbih + 1500, dbhh + 1500, h1out);
  gbar(bcnt, bgen, 32);

  // ---- phase C: attention scores (rnn = h1out) ----
  for (int i = tid; i < 500; i += 1024) x_lds[i] = h1out[i];
  __syncthreads();
  if (wid < 8) {
    int s = blk * 8 + wid;
    const float* row = enc_out + (size_t)s * 500;
    float acc = 0.f;
    #pragma unroll
    for (int j = 0; j < 8; ++j) {
      int k = lane + 64 * j;
      if (k < 500) acc += row[k] * x_lds[k];
    }
    acc = wred(acc);
    if (lane == 0) scores[s] = acc;
  }
  gbar(bcnt, bgen, 32);

  // ---- phase D: softmax (each block computes full softmax) + ctx slice ----
  float myv = 0.f;
  if (tid < 256) { myv = scores[tid]; red[tid] = myv; }
  __syncthreads();
  for (int s = 128; s > 0; s >>= 1) {
    if (tid < s) red[tid] = fmaxf(red[tid], red[tid + s]);
    __syncthreads();
  }
  float m = red[0]; __syncthreads();
  float e = 0.f;
  if (tid < 256) { e = expf(myv - m); red[tid] = e; }
  __syncthreads();
  for (int s = 128; s > 0; s >>= 1) {
    if (tid < s) red[tid] += red[tid + s];
    __syncthreads();
  }
  float inv = 1.f / red[0]; __syncthreads();
  if (tid < 256) sc_lds[tid] = e * inv;
  __syncthreads();
  {
    int j = blk * 16 + wid;
    if (j < 500) {
      float acc = 0.f;
      #pragma unroll
      for (int q = 0; q < 4; ++q) {
        int s = lane + 64 * q;
        acc += sc_lds[s] * enc_out[(size_t)s * 500 + j];
      }
      acc = wred(acc);
      if (lane == 0) ctx[j] = acc;
    }
  }
  gbar(bcnt, bgen, 32);

  // ---- phase E: cvec = tanh(concat_W @ [rnn; ctx] + concat_b) ----
  for (int i = tid; i < 500; i += 1024) h_lds[i] = ctx[i];   // x_lds still holds rnn
  __syncthreads();
  {
    int i = blk * 16 + wid;
    if (i < 500) {
      const float* row = cW + (size_t)i * 1000;
      float acc = 0.f;
      #pragma unroll
      for (int j = 0; j < 16; ++j) {
        int k = lane + 64 * j;
        if (k < 1000) {
          float v = (k < 500) ? x_lds[k] : h_lds[k - 500];
          acc += row[k] * v;
        }
      }
      acc = wred(acc);
      if (lane == 0) cvec[i] = tanhf(acc + cb[i]);
    }
  }
}

// ---------------- logits = out_W @ c + out_b, per-block max/argmax ----------------
__global__ __launch_bounds__(1024) void logits_k(const float* __restrict__ outW,
                                                 const float* __restrict__ outb,
                                                 const float* __restrict__ cvec,
                                                 float* __restrict__ logits,
                                                 float* __restrict__ pmax,
                                                 int* __restrict__ pidx) {
  __shared__ float4 c4[125];
  __shared__ float lmax[16];
  __shared__ int   lidx[16];
  if (threadIdx.x < 125) c4[threadIdx.x] = ((const float4*)cvec)[threadIdx.x];
  __syncthreads();
  int wid = threadIdx.x >> 6, lane = threadIdx.x & 63;
  int gw = blockIdx.x * 16 + wid;
  float bm = -INFINITY; int bi = V;
  #pragma unroll
  for (int rr = 0; rr < 4; ++rr) {
    int row = gw * 4 + rr;
    if (row < V) {
      const float4* wrow = (const float4*)(outW + (size_t)row * 500);
      float acc = 0.f;
      #pragma unroll
      for (int q = 0; q < 2; ++q) {
        int k4 = lane + 64 * q;
        if (k4 < 125) {
          float4 w4 = wrow[k4]; float4 cc = c4[k4];
          acc += w4.x * cc.x + w4.y * cc.y + w4.z * cc.z + w4.w * cc.w;
        }
      }
      acc = wred(acc);
      if (lane == 0) {
        float l = acc + outb[row];
        logits[row] = l;
        if (l > bm) { bm = l; bi = row; }
      }
    }
  }
  if (lane == 0) { lmax[wid] = bm; lidx[wid] = bi; }
  __syncthreads();
  if (threadIdx.x == 0) {
    float m = -INFINITY; int ix = V;
    for (int wq = 0; wq < 16; ++wq) {
      if (lmax[wq] > m || (lmax[wq] == m && lidx[wq] < ix)) { m = lmax[wq]; ix = lidx[wq]; }
    }
    pmax[blockIdx.x] = m; pidx[blockIdx.x] = ix;
  }
}

// ---------------- global argmax + softmax + write outputs ----------------
__global__ __launch_bounds__(1024) void finalize_k(const float* __restrict__ pmax,
                                                   const int* __restrict__ pidx, int nblk,
                                                   float* __restrict__ logits,
                                                   int* __restrict__ tok,
                                                   float* __restrict__ out_tokens,
                                                   float* __restrict__ out_probs, int step) {
  __shared__ float rm[1024];
  __shared__ int   ri[1024];
  int tid = threadIdx.x;
  float m = -INFINITY; int ix = V;
  for (int b = tid; b < nblk; b += 1024) {
    float v = pmax[b]; int id = pidx[b];
    if (v > m || (v == m && id < ix)) { m = v; ix = id; }
  }
  rm[tid] = m; ri[tid] = ix; __syncthreads();
  for (int s = 512; s > 0; s >>= 1) {
    if (tid < s) {
      if (rm[tid + s] > rm[tid] || (rm[tid + s] == rm[tid] && ri[tid + s] < ri[tid])) {
        rm[tid] = rm[tid + s]; ri[tid] = ri[tid + s];
      }
    }
    __syncthreads();
  }
  float gmax = rm[0]; int gidx = ri[0];
  __syncthreads();
  if (tid == 0) { tok[0] = gidx; out_tokens[step] = (float)gidx; }
  float sum = 0.f;
  for (int v = tid; v < V; v += 1024) {
    float e = expf(logits[v] - gmax);
    logits[v] = e;
    sum += e;
  }
  rm[tid] = sum; __syncthreads();
  for (int s = 512; s > 0; s >>= 1) {
    if (tid < s) rm[tid] += rm[tid + s];
    __syncthreads();
  }
  float inv = 1.f / rm[0];
  for (int v = tid; v < V; v += 1024)
    out_probs[(size_t)step * V + v] = logits[v] * inv;
}

extern "C" void kernel_launch(void* const* d_in, const int* in_sizes, int n_in,
                              void* d_out, int out_size, void* d_ws, size_t ws_size,
                              hipStream_t stream) {
  const int*   seq   = (const int*)d_in[0];
  const float* emb   = (const float*)d_in[3];
  const float* e0f_Wih = (const float*)d_in[4];
  const float* e0f_Whh = (const float*)d_in[5];
  const float* e0f_bih = (const float*)d_in[6];
  const float* e0f_bhh = (const float*)d_in[7];
  const float* e0b_Wih = (const float*)d_in[8];
  const float* e0b_Whh = (const float*)d_in[9];
  const float* e0b_bih = (const float*)d_in[10];
  const float* e0b_bhh = (const float*)d_in[11];
  const float* e1f_Wih = (const float*)d_in[12];
  const float* e1f_Whh = (const float*)d_in[13];
  const float* e1f_bih = (const float*)d_in[14];
  const float* e1f_bhh = (const float*)d_in[15];
  const float* e1b_Wih = (const float*)d_in[16];
  const float* e1b_Whh = (const float*)d_in[17];
  const float* e1b_bih = (const float*)d_in[18];
  const float* e1b_bhh = (const float*)d_in[19];
  const float* dWih = (const float*)d_in[20];
  const float* dWhh = (const float*)d_in[21];
  const float* dbih = (const float*)d_in[22];
  const float* dbhh = (const float*)d_in[23];
  const float* cW   = (const float*)d_in[24];
  const float* cb   = (const float*)d_in[25];
  const float* outW = (const float*)d_in[26];
  const float* outb = (const float*)d_in[27];

  float* w = (float*)d_ws;
  float* ex      = w;                      // 128000
  float* x1      = ex + 128000;            // 256000
  float* gxf     = x1 + 256000;            // 384000
  float* gxb     = gxf + 384000;           // 384000
  float* y1f     = gxb + 384000;           // 128000
  float* y1b     = y1f + 128000;           // 128000
  float* enc_out = y1b + 128000;           // 128000
  float* hb      = enc_out + 128000;       // 8 x 512 h ping-pong buffers
  float* hL0FA = hb;          float* hL0FB = hb + 512;
  float* hL0BA = hb + 1024;   float* hL0BB = hb + 1536;
  float* hL1FA = hb + 2048;   float* hL1FB = hb + 2560;
  float* hL1BA = hb + 3072;   float* hL1BB = hb + 3584;
  float* dsc0   = hb + 4096;               // 512
  float* dsc1   = dsc0 + 512;              // 512
  float* scores = dsc1 + 512;              // 512
  float* ctx    = scores + 512;            // 512
  float* cvec   = ctx + 512;               // 512
  float* logits = cvec + 512;              // 50432
  float* pmax   = logits + 50432;          // 1024
  int*   pidx   = (int*)(pmax + 1024);     // 1024 ints
  int*   tokp   = pidx + 1024;             // a few ints
  int*   bar    = tokp + 64;               // barrier counters: scnt,sgen,dcnt,dgen

  float* outf = (float*)d_out;

  // zero barrier counters (d_ws is re-poisoned before every call)
  hipMemsetAsync(bar, 0, 4 * sizeof(int), stream);

  init_k<<<1, 64, 0, stream>>>(tokp);
  embed_k<<<SEQ, 128, 0, stream>>>(seq, emb, ex);

  // encoder layer 0: gate-input GEMMs, then persistent scan (fwd+bwd in one launch)
  gemm_nt<<<dim3(24, 4), 256, 0, stream>>>(ex, e0f_Wih, e0f_bih, gxf, SEQ, H3, H);
  gemm_nt<<<dim3(24, 4), 256, 0, stream>>>(ex, e0b_Wih, e0b_bih, gxb, SEQ, H3, H);
  gru_scan_persist<<<2 * SB, 512, 0, stream>>>(gxf, gxb, e0f_Whh, e0b_Whh,
      e0f_bhh, e0b_bhh, hL0FA, hL0FB, hL0BA, hL0BB, x1, x1 + 500, 1000,
      bar + 0, bar + 1);

  // encoder layer 1
  gemm_nt<<<dim3(24, 4), 256, 0, stream>>>(x1, e1f_Wih, e1f_bih, gxf, SEQ, H3, 2 * H);
  gemm_nt<<<dim3(24, 4), 256, 0, stream>>>(x1, e1b_Wih, e1b_bih, gxb, SEQ, H3, 2 * H);
  gru_scan_persist<<<2 * SB, 512, 0, stream>>>(gxf, gxb, e1f_Whh, e1b_Whh,
      e1f_bhh, e1b_bhh, hL1FA, hL1FB, hL1BA, hL1BB, y1f, y1b, 500,
      bar + 0, bar + 1);
  add_k<<<(SEQ * H + 255) / 256, 256, 0, stream>>>(y1f, y1b, enc_out, SEQ * H);

  // decoder: h ping-pong (layer0 init = final fwd hidden of enc layer0 = hL0FA;
  // layer1 init = final bwd hidden = hL0BA; both land in buffer A after 256 steps)
  float* h0c = hL0FA; float* h0a = dsc0;
  float* h1c = hL0BA; float* h1a = dsc1;
  for (int st = 0; st < TDEC; ++st) {
    dec_step_fused<<<32, 1024, 0, stream>>>(tokp, emb, h0c, h0a, h1c, h1a,
        dWih, dWhh, dbih, dbhh, enc_out, cW, cb, scores, ctx, cvec,
        bar + 2, bar + 3);
    float* t0 = h0c; h0c = h0a; h0a = t0;
    float* t1 = h1c; h1c = h1a; h1a = t1;
    logits_k<<<NLB, 1024, 0, stream>>>(outW, outb, cvec, logits, pmax, pidx);
    finalize_k<<<1, 1024, 0, stream>>>(pmax, pidx, NLB, logits, tokp,
        outf, outf + TDEC, st);
  }
}

// Round 3
// 11740.944 us; speedup vs baseline: 1.1015x; 1.1015x over previous
//
#include <hip/hip_runtime.h>
#include <math.h>

constexpr int H    = 500;
constexpr int H3   = 1500;
constexpr int SEQ  = 256;
constexpr int V    = 50257;
constexpr int TDEC = 64;
constexpr int NLB  = (V + 63) / 64;   // logits blocks: 64 rows per block
constexpr int SB   = 50;              // scan blocks per direction
constexpr int UPB  = 10;              // hidden units per scan block

__device__ __forceinline__ float sigmoidf_(float x) { return 1.f / (1.f + expf(-x)); }

__device__ __forceinline__ float wred(float v) {
  #pragma unroll
  for (int off = 32; off > 0; off >>= 1) v += __shfl_down(v, off, 64);
  return v;
}

// ---------------- software grid barrier (device scope, relaxed spin) ----------------
// R2 post-mortem: SEQ_CST load in the spin loop = acquire fence (cache invalidate)
// per poll per block -> 13.5us/barrier. Fix: relaxed spin, fences only at the edges.
__device__ __forceinline__ void gbar(int* cnt, int* gen, int nblk) {
  __syncthreads();
  if (threadIdx.x == 0) {
    __threadfence();   // release: publish this block's writes
    int g = __hip_atomic_load(gen, __ATOMIC_RELAXED, __HIP_MEMORY_SCOPE_AGENT);
    int prev = __hip_atomic_fetch_add(cnt, 1, __ATOMIC_ACQ_REL, __HIP_MEMORY_SCOPE_AGENT);
    if (prev == nblk - 1) {
      // last arriver: reset count, then release-publish new generation.
      __hip_atomic_store(cnt, 0, __ATOMIC_RELAXED, __HIP_MEMORY_SCOPE_AGENT);
      __hip_atomic_fetch_add(gen, 1, __ATOMIC_RELEASE, __HIP_MEMORY_SCOPE_AGENT);
    } else {
      while (__hip_atomic_load(gen, __ATOMIC_RELAXED, __HIP_MEMORY_SCOPE_AGENT) == g)
        __builtin_amdgcn_s_sleep(1);
      __threadfence(); // acquire: see everyone's writes
    }
  }
  __syncthreads();
}

// ---------------- init: tok = SOS ----------------
__global__ void init_k(int* tok) {
  if (threadIdx.x == 0) tok[0] = 1;  // SOS
}

// ---------------- embedding lookup: ex[t] = emb[seq[t]] ----------------
__global__ void embed_k(const int* __restrict__ seq, const float* __restrict__ emb,
                        float* __restrict__ ex) {
  int t = blockIdx.x;
  int tok = seq[t];
  for (int i = threadIdx.x; i < H; i += blockDim.x)
    ex[(size_t)t * H + i] = emb[(size_t)tok * H + i];
}

// ---------------- C[m][n] = bias[n] + sum_k X[m*K+k] * W[n*K+k] ----------------
__global__ __launch_bounds__(256) void gemm_nt(const float* __restrict__ X,
                                               const float* __restrict__ W,
                                               const float* __restrict__ bias,
                                               float* __restrict__ C,
                                               int M, int N, int K) {
  __shared__ float Xs[64][17];
  __shared__ float Ws[64][17];
  int bm = blockIdx.y * 64, bn = blockIdx.x * 64;
  int tid = threadIdx.x;
  int tx = tid % 16, ty = tid / 16;
  float acc[4][4] = {};
  for (int k0 = 0; k0 < K; k0 += 16) {
    for (int i = tid; i < 64 * 16; i += 256) {
      int m = i / 16, k = i % 16;
      int gm = bm + m, gk = k0 + k, gn = bn + m;
      Xs[m][k] = (gm < M && gk < K) ? X[(size_t)gm * K + gk] : 0.f;
      Ws[m][k] = (gn < N && gk < K) ? W[(size_t)gn * K + gk] : 0.f;
    }
    __syncthreads();
    #pragma unroll
    for (int k = 0; k < 16; ++k) {
      float xv[4], wv[4];
      #pragma unroll
      for (int i = 0; i < 4; ++i) xv[i] = Xs[ty * 4 + i][k];
      #pragma unroll
      for (int j = 0; j < 4; ++j) wv[j] = Ws[tx * 4 + j][k];
      #pragma unroll
      for (int i = 0; i < 4; ++i)
        #pragma unroll
        for (int j = 0; j < 4; ++j) acc[i][j] += xv[i] * wv[j];
    }
    __syncthreads();
  }
  for (int i = 0; i < 4; ++i) {
    int gm = bm + ty * 4 + i;
    if (gm >= M) continue;
    for (int j = 0; j < 4; ++j) {
      int gn = bn + tx * 4 + j;
      if (gn >= N) continue;
      C[(size_t)gm * N + gn] = acc[i][j] + bias[gn];
    }
  }
}

// ---------------- persistent GRU scan: one launch per layer, fwd+bwd ----------------
__global__ __launch_bounds__(512, 1) void gru_scan_persist(
    const float* __restrict__ gxF, const float* __restrict__ gxB,
    const float* __restrict__ WhhF, const float* __restrict__ WhhB,
    const float* __restrict__ bhhF, const float* __restrict__ bhhB,
    float* __restrict__ hFA, float* __restrict__ hFB,
    float* __restrict__ hBA, float* __restrict__ hBB,
    float* __restrict__ yF, float* __restrict__ yB, int ystride,
    int* bcnt, int* bgen) {
  __shared__ float w_lds[30 * 500];   // 60 KB
  __shared__ float gates[32];
  int dir = blockIdx.x / SB;
  int bu  = blockIdx.x % SB;
  int u0  = bu * UPB;
  const float* gx  = dir ? gxB : gxF;
  const float* Whh = dir ? WhhB : WhhF;
  const float* bhh = dir ? bhhB : bhhF;
  float* hA = dir ? hBA : hFA;
  float* hB = dir ? hBB : hFB;
  float* y  = dir ? yB : yF;
  int tid = threadIdx.x, lane = tid & 63, wid = tid >> 6;

  // stage this block's Whh rows into LDS
  for (int idx = tid; idx < 30 * 500; idx += 512) {
    int r = idx / 500, k = idx - r * 500;
    int g = r / UPB, lu = r - g * UPB;
    w_lds[idx] = Whh[(size_t)(g * 500 + u0 + lu) * 500 + k];
  }
  __syncthreads();

  float hreg[8];
  for (int t = 0; t < SEQ; ++t) {
    const float* hin  = (t & 1) ? hB : hA;
    float*       hout = (t & 1) ? hA : hB;
    int teff = dir ? (SEQ - 1 - t) : t;
    #pragma unroll
    for (int j = 0; j < 8; ++j) {
      int k = lane + 64 * j;
      hreg[j] = (t > 0 && k < 500) ? hin[k] : 0.f;
    }
    for (int r = wid; r < 30; r += 8) {
      const float* wr = &w_lds[r * 500];
      float acc = 0.f;
      #pragma unroll
      for (int j = 0; j < 8; ++j) {
        int k = lane + 64 * j;
        if (k < 500) acc += wr[k] * hreg[j];
      }
      acc = wred(acc);
      if (lane == 0) gates[r] = acc;
    }
    __syncthreads();
    if (tid < UPB) {
      int u = u0 + tid;
      float hold = (t > 0) ? hin[u] : 0.f;
      const float* g = gx + (size_t)teff * H3;
      float rr = sigmoidf_(g[u]        + gates[tid]           + bhh[u]);
      float zz = sigmoidf_(g[500 + u]  + gates[UPB + tid]     + bhh[500 + u]);
      float nn = tanhf(    g[1000 + u] + rr * (gates[2 * UPB + tid] + bhh[1000 + u]));
      float hp = (1.f - zz) * nn + zz * hold;
      hout[u] = hp;
      y[(size_t)teff * ystride + u] = hp;
    }
    if (t < SEQ - 1) gbar(bcnt, bgen, 2 * SB);
  }
}

// ---------------- enc_out = y1f + y1b ----------------
__global__ void add_k(const float* __restrict__ a, const float* __restrict__ b,
                      float* __restrict__ c, int n) {
  int i = blockIdx.x * blockDim.x + threadIdx.x;
  if (i < n) c[i] = a[i] + b[i];
}

// ---------------- fused decoder step (cells + attention + concat) ----------------
__device__ __forceinline__ void cell_phase(int blk, int wid, int lane, int tid,
    const float* x_lds, const float* h_lds, float* gates,
    const float* Wih, const float* Whh, const float* bih, const float* bhh,
    float* hout) {
  for (int rr = wid; rr < 96; rr += 16) {
    int lu = rr & 15, kind = rr >> 4;
    int u = blk * 16 + lu;
    if (u < 500) {
      const float* row = (kind < 3) ? (Wih + (size_t)(kind * 500 + u) * 500)
                                    : (Whh + (size_t)((kind - 3) * 500 + u) * 500);
      const float* vec = (kind < 3) ? x_lds : h_lds;
      float acc = 0.f;
      #pragma unroll
      for (int j = 0; j < 8; ++j) {
        int k = lane + 64 * j;
        if (k < 500) acc += row[k] * vec[k];
      }
      acc = wred(acc);
      if (lane == 0) gates[rr] = acc;
    }
  }
  __syncthreads();
  if (tid < 16) {
    int u = blk * 16 + tid;
    if (u < 500) {
      float sxr = gates[tid],      sxz = gates[16 + tid], sxn = gates[32 + tid];
      float shr = gates[48 + tid], shz = gates[64 + tid], shn = gates[80 + tid];
      float r = sigmoidf_(sxr + bih[u]        + shr + bhh[u]);
      float z = sigmoidf_(sxz + bih[500 + u]  + shz + bhh[500 + u]);
      float n = tanhf(    sxn + bih[1000 + u] + r * (shn + bhh[1000 + u]));
      hout[u] = (1.f - z) * n + z * h_lds[u];
    }
  }
}

__global__ __launch_bounds__(1024, 1) void dec_step_fused(
    const int* __restrict__ tok, const float* __restrict__ emb,
    const float* __restrict__ h0in, float* __restrict__ h0out,
    const float* __restrict__ h1in, float* __restrict__ h1out,
    const float* __restrict__ dWih, const float* __restrict__ dWhh,
    const float* __restrict__ dbih, const float* __restrict__ dbhh,
    const float* __restrict__ enc_out, const float* __restrict__ cW,
    const float* __restrict__ cb,
    float* __restrict__ scores, float* __restrict__ ctx, float* __restrict__ cvec,
    int* bcnt, int* bgen) {
  __shared__ float x_lds[512], h_lds[512], gates[96], red[256], sc_lds[256];
  int tid = threadIdx.x, lane = tid & 63, wid = tid >> 6, blk = blockIdx.x;

  // ---- phase A: layer-0 GRU cell (x = emb[tok]) ----
  int tk = tok[0];
  for (int i = tid; i < 500; i += 1024) {
    x_lds[i] = emb[(size_t)tk * 500 + i];
    h_lds[i] = h0in[i];
  }
  __syncthreads();
  cell_phase(blk, wid, lane, tid, x_lds, h_lds, gates, dWih, dWhh, dbih, dbhh, h0out);
  gbar(bcnt, bgen, 32);

  // ---- phase B: layer-1 GRU cell (x = h0out) ----
  for (int i = tid; i < 500; i += 1024) {
    x_lds[i] = h0out[i];
    h_lds[i] = h1in[i];
  }
  __syncthreads();
  cell_phase(blk, wid, lane, tid, x_lds, h_lds, gates,
             dWih + 750000, dWhh + 750000, dbih + 1500, dbhh + 1500, h1out);
  gbar(bcnt, bgen, 32);

  // ---- phase C: attention scores (rnn = h1out) ----
  for (int i = tid; i < 500; i += 1024) x_lds[i] = h1out[i];
  __syncthreads();
  if (wid < 8) {
    int s = blk * 8 + wid;
    const float* row = enc_out + (size_t)s * 500;
    float acc = 0.f;
    #pragma unroll
    for (int j = 0; j < 8; ++j) {
      int k = lane + 64 * j;
      if (k < 500) acc += row[k] * x_lds[k];
    }
    acc = wred(acc);
    if (lane == 0) scores[s] = acc;
  }
  gbar(bcnt, bgen, 32);

  // ---- phase D: softmax (each block computes full softmax) + ctx slice ----
  float myv = 0.f;
  if (tid < 256) { myv = scores[tid]; red[tid] = myv; }
  __syncthreads();
  for (int s = 128; s > 0; s >>= 1) {
    if (tid < s) red[tid] = fmaxf(red[tid], red[tid + s]);
    __syncthreads();
  }
  float m = red[0]; __syncthreads();
  float e = 0.f;
  if (tid < 256) { e = expf(myv - m); red[tid] = e; }
  __syncthreads();
  for (int s = 128; s > 0; s >>= 1) {
    if (tid < s) red[tid] += red[tid + s];
    __syncthreads();
  }
  float inv = 1.f / red[0]; __syncthreads();
  if (tid < 256) sc_lds[tid] = e * inv;
  __syncthreads();
  {
    int j = blk * 16 + wid;
    if (j < 500) {
      float acc = 0.f;
      #pragma unroll
      for (int q = 0; q < 4; ++q) {
        int s = lane + 64 * q;
        acc += sc_lds[s] * enc_out[(size_t)s * 500 + j];
      }
      acc = wred(acc);
      if (lane == 0) ctx[j] = acc;
    }
  }
  gbar(bcnt, bgen, 32);

  // ---- phase E: cvec = tanh(concat_W @ [rnn; ctx] + concat_b) ----
  for (int i = tid; i < 500; i += 1024) h_lds[i] = ctx[i];   // x_lds still holds rnn
  __syncthreads();
  {
    int i = blk * 16 + wid;
    if (i < 500) {
      const float* row = cW + (size_t)i * 1000;
      float acc = 0.f;
      #pragma unroll
      for (int j = 0; j < 16; ++j) {
        int k = lane + 64 * j;
        if (k < 1000) {
          float v = (k < 500) ? x_lds[k] : h_lds[k - 500];
          acc += row[k] * v;
        }
      }
      acc = wred(acc);
      if (lane == 0) cvec[i] = tanhf(acc + cb[i]);
    }
  }
}

// ---------------- logits = out_W @ c + out_b, per-block max/argmax ----------------
__global__ __launch_bounds__(1024) void logits_k(const float* __restrict__ outW,
                                                 const float* __restrict__ outb,
                                                 const float* __restrict__ cvec,
                                                 float* __restrict__ logits,
                                                 float* __restrict__ pmax,
                                                 int* __restrict__ pidx) {
  __shared__ float4 c4[125];
  __shared__ float lmax[16];
  __shared__ int   lidx[16];
  if (threadIdx.x < 125) c4[threadIdx.x] = ((const float4*)cvec)[threadIdx.x];
  __syncthreads();
  int wid = threadIdx.x >> 6, lane = threadIdx.x & 63;
  int gw = blockIdx.x * 16 + wid;
  float bm = -INFINITY; int bi = V;
  #pragma unroll
  for (int rr = 0; rr < 4; ++rr) {
    int row = gw * 4 + rr;
    if (row < V) {
      const float4* wrow = (const float4*)(outW + (size_t)row * 500);
      float acc = 0.f;
      #pragma unroll
      for (int q = 0; q < 2; ++q) {
        int k4 = lane + 64 * q;
        if (k4 < 125) {
          float4 w4 = wrow[k4]; float4 cc = c4[k4];
          acc += w4.x * cc.x + w4.y * cc.y + w4.z * cc.z + w4.w * cc.w;
        }
      }
      acc = wred(acc);
      if (lane == 0) {
        float l = acc + outb[row];
        logits[row] = l;
        if (l > bm) { bm = l; bi = row; }
      }
    }
  }
  if (lane == 0) { lmax[wid] = bm; lidx[wid] = bi; }
  __syncthreads();
  if (threadIdx.x == 0) {
    float m = -INFINITY; int ix = V;
    for (int wq = 0; wq < 16; ++wq) {
      if (lmax[wq] > m || (lmax[wq] == m && lidx[wq] < ix)) { m = lmax[wq]; ix = lidx[wq]; }
    }
    pmax[blockIdx.x] = m; pidx[blockIdx.x] = ix;
  }
}

// ---------------- global argmax + softmax + write outputs ----------------
__global__ __launch_bounds__(1024) void finalize_k(const float* __restrict__ pmax,
                                                   const int* __restrict__ pidx, int nblk,
                                                   float* __restrict__ logits,
                                                   int* __restrict__ tok,
                                                   float* __restrict__ out_tokens,
                                                   float* __restrict__ out_probs, int step) {
  __shared__ float rm[1024];
  __shared__ int   ri[1024];
  int tid = threadIdx.x;
  float m = -INFINITY; int ix = V;
  for (int b = tid; b < nblk; b += 1024) {
    float v = pmax[b]; int id = pidx[b];
    if (v > m || (v == m && id < ix)) { m = v; ix = id; }
  }
  rm[tid] = m; ri[tid] = ix; __syncthreads();
  for (int s = 512; s > 0; s >>= 1) {
    if (tid < s) {
      if (rm[tid + s] > rm[tid] || (rm[tid + s] == rm[tid] && ri[tid + s] < ri[tid])) {
        rm[tid] = rm[tid + s]; ri[tid] = ri[tid + s];
      }
    }
    __syncthreads();
  }
  float gmax = rm[0]; int gidx = ri[0];
  __syncthreads();
  if (tid == 0) { tok[0] = gidx; out_tokens[step] = (float)gidx; }
  float sum = 0.f;
  for (int v = tid; v < V; v += 1024) {
    float e = expf(logits[v] - gmax);
    logits[v] = e;
    sum += e;
  }
  rm[tid] = sum; __syncthreads();
  for (int s = 512; s > 0; s >>= 1) {
    if (tid < s) rm[tid] += rm[tid + s];
    __syncthreads();
  }
  float inv = 1.f / rm[0];
  for (int v = tid; v < V; v += 1024)
    out_probs[(size_t)step * V + v] = logits[v] * inv;
}

extern "C" void kernel_launch(void* const* d_in, const int* in_sizes, int n_in,
                              void* d_out, int out_size, void* d_ws, size_t ws_size,
                              hipStream_t stream) {
  const int*   seq   = (const int*)d_in[0];
  const float* emb   = (const float*)d_in[3];
  const float* e0f_Wih = (const float*)d_in[4];
  const float* e0f_Whh = (const float*)d_in[5];
  const float* e0f_bih = (const float*)d_in[6];
  const float* e0f_bhh = (const float*)d_in[7];
  const float* e0b_Wih = (const float*)d_in[8];
  const float* e0b_Whh = (const float*)d_in[9];
  const float* e0b_bih = (const float*)d_in[10];
  const float* e0b_bhh = (const float*)d_in[11];
  const float* e1f_Wih = (const float*)d_in[12];
  const float* e1f_Whh = (const float*)d_in[13];
  const float* e1f_bih = (const float*)d_in[14];
  const float* e1f_bhh = (const float*)d_in[15];
  const float* e1b_Wih = (const float*)d_in[16];
  const float* e1b_Whh = (const float*)d_in[17];
  const float* e1b_bih = (const float*)d_in[18];
  const float* e1b_bhh = (const float*)d_in[19];
  const float* dWih = (const float*)d_in[20];
  const float* dWhh = (const float*)d_in[21];
  const float* dbih = (const float*)d_in[22];
  const float* dbhh = (const float*)d_in[23];
  const float* cW   = (const float*)d_in[24];
  const float* cb   = (const float*)d_in[25];
  const float* outW = (const float*)d_in[26];
  const float* outb = (const float*)d_in[27];

  float* w = (float*)d_ws;
  float* ex      = w;                      // 128000
  float* x1      = ex + 128000;            // 256000
  float* gxf     = x1 + 256000;            // 384000
  float* gxb     = gxf + 384000;           // 384000
  float* y1f     = gxb + 384000;           // 128000
  float* y1b     = y1f + 128000;           // 128000
  float* enc_out = y1b + 128000;           // 128000
  float* hb      = enc_out + 128000;       // 8 x 512 h ping-pong buffers
  float* hL0FA = hb;          float* hL0FB = hb + 512;
  float* hL0BA = hb + 1024;   float* hL0BB = hb + 1536;
  float* hL1FA = hb + 2048;   float* hL1FB = hb + 2560;
  float* hL1BA = hb + 3072;   float* hL1BB = hb + 3584;
  float* dsc0   = hb + 4096;               // 512
  float* dsc1   = dsc0 + 512;              // 512
  float* scores = dsc1 + 512;              // 512
  float* ctx    = scores + 512;            // 512
  float* cvec   = ctx + 512;               // 512
  float* logits = cvec + 512;              // 50432
  float* pmax   = logits + 50432;          // 1024
  int*   pidx   = (int*)(pmax + 1024);     // 1024 ints
  int*   tokp   = pidx + 1024;             // a few ints
  int*   bar    = tokp + 64;               // barrier counters: scnt,sgen,dcnt,dgen

  float* outf = (float*)d_out;

  // zero barrier counters (d_ws is re-poisoned before every call)
  hipMemsetAsync(bar, 0, 4 * sizeof(int), stream);

  init_k<<<1, 64, 0, stream>>>(tokp);
  embed_k<<<SEQ, 128, 0, stream>>>(seq, emb, ex);

  // encoder layer 0: gate-input GEMMs, then persistent scan (fwd+bwd in one launch)
  gemm_nt<<<dim3(24, 4), 256, 0, stream>>>(ex, e0f_Wih, e0f_bih, gxf, SEQ, H3, H);
  gemm_nt<<<dim3(24, 4), 256, 0, stream>>>(ex, e0b_Wih, e0b_bih, gxb, SEQ, H3, H);
  gru_scan_persist<<<2 * SB, 512, 0, stream>>>(gxf, gxb, e0f_Whh, e0b_Whh,
      e0f_bhh, e0b_bhh, hL0FA, hL0FB, hL0BA, hL0BB, x1, x1 + 500, 1000,
      bar + 0, bar + 1);

  // encoder layer 1
  gemm_nt<<<dim3(24, 4), 256, 0, stream>>>(x1, e1f_Wih, e1f_bih, gxf, SEQ, H3, 2 * H);
  gemm_nt<<<dim3(24, 4), 256, 0, stream>>>(x1, e1b_Wih, e1b_bih, gxb, SEQ, H3, 2 * H);
  gru_scan_persist<<<2 * SB, 512, 0, stream>>>(gxf, gxb, e1f_Whh, e1b_Whh,
      e1f_bhh, e1b_bhh, hL1FA, hL1FB, hL1BA, hL1BB, y1f, y1b, 500,
      bar + 0, bar + 1);
  add_k<<<(SEQ * H + 255) / 256, 256, 0, stream>>>(y1f, y1b, enc_out, SEQ * H);

  // decoder: h ping-pong
  float* h0c = hL0FA; float* h0a = dsc0;
  float* h1c = hL0BA; float* h1a = dsc1;
  for (int st = 0; st < TDEC; ++st) {
    dec_step_fused<<<32, 1024, 0, stream>>>(tokp, emb, h0c, h0a, h1c, h1a,
        dWih, dWhh, dbih, dbhh, enc_out, cW, cb, scores, ctx, cvec,
        bar + 2, bar + 3);
    float* t0 = h0c; h0c = h0a; h0a = t0;
    float* t1 = h1c; h1c = h1a; h1a = t1;
    logits_k<<<NLB, 1024, 0, stream>>>(outW, outb, cvec, logits, pmax, pidx);
    finalize_k<<<1, 1024, 0, stream>>>(pmax, pidx, NLB, logits, tokp,
        outf, outf + TDEC, st);
  }
}

// Round 4
// 7754.995 us; speedup vs baseline: 1.6676x; 1.5140x over previous
//
#include <hip/hip_runtime.h>
#include <math.h>

constexpr int H    = 500;
constexpr int H3   = 1500;
constexpr int SEQ  = 256;
constexpr int V    = 50257;
constexpr int TDEC = 64;
constexpr int NLB  = (V + 63) / 64;   // logits blocks: 64 rows per block
constexpr int SB   = 50;              // scan blocks per direction
constexpr int UPB  = 10;              // hidden units per scan block

__device__ __forceinline__ float sigmoidf_(float x) { return 1.f / (1.f + expf(-x)); }

__device__ __forceinline__ float wred(float v) {
  #pragma unroll
  for (int off = 32; off > 0; off >>= 1) v += __shfl_down(v, off, 64);
  return v;
}

// Coherent (LLC-routed, L2-bypassing) scalar accesses for cross-block data.
// Relaxed agent-scope atomics compile to sc1 loads/stores: no wbl2/inv needed.
__device__ __forceinline__ float gload(const float* p) {
  return __hip_atomic_load((float*)p, __ATOMIC_RELAXED, __HIP_MEMORY_SCOPE_AGENT);
}
__device__ __forceinline__ void gstore(float* p, float v) {
  __hip_atomic_store(p, v, __ATOMIC_RELAXED, __HIP_MEMORY_SCOPE_AGENT);
}

// ---------------- fence-free grid barrier ----------------
// R3 post-mortem: __threadfence() = agent fence = full L2 writeback/invalidate
// per block per barrier (L2s are per-XCD non-coherent). With all shared data
// going through sc1 (gload/gstore), no cache maintenance is needed; ordering
// comes from s_waitcnt (stores acked at LLC before arrival / gen bump).
__device__ __forceinline__ void gbar(int* cnt, int* gen, int nblk) {
  __builtin_amdgcn_s_waitcnt(0);   // this wave's sc1 stores are at the LLC
  __syncthreads();                 // all waves of block drained (compiler adds waitcnt)
  if (threadIdx.x == 0) {
    int g = __hip_atomic_load(gen, __ATOMIC_RELAXED, __HIP_MEMORY_SCOPE_AGENT);
    int prev = __hip_atomic_fetch_add(cnt, 1, __ATOMIC_RELAXED, __HIP_MEMORY_SCOPE_AGENT);
    if (prev == nblk - 1) {
      __hip_atomic_store(cnt, 0, __ATOMIC_RELAXED, __HIP_MEMORY_SCOPE_AGENT);
      __builtin_amdgcn_s_waitcnt(0);   // cnt reset visible before gen bump
      __hip_atomic_store(gen, g + 1, __ATOMIC_RELAXED, __HIP_MEMORY_SCOPE_AGENT);
    } else {
      while (__hip_atomic_load(gen, __ATOMIC_RELAXED, __HIP_MEMORY_SCOPE_AGENT) == g)
        __builtin_amdgcn_s_sleep(2);
    }
  }
  __syncthreads();
}

// ---------------- init: tok = SOS ----------------
__global__ void init_k(int* tok) {
  if (threadIdx.x == 0) tok[0] = 1;  // SOS
}

// ---------------- embedding lookup: ex[t] = emb[seq[t]] ----------------
__global__ void embed_k(const int* __restrict__ seq, const float* __restrict__ emb,
                        float* __restrict__ ex) {
  int t = blockIdx.x;
  int tok = seq[t];
  for (int i = threadIdx.x; i < H; i += blockDim.x)
    ex[(size_t)t * H + i] = emb[(size_t)tok * H + i];
}

// ---------------- C[m][n] = bias[n] + sum_k X[m*K+k] * W[n*K+k] ----------------
__global__ __launch_bounds__(256) void gemm_nt(const float* __restrict__ X,
                                               const float* __restrict__ W,
                                               const float* __restrict__ bias,
                                               float* __restrict__ C,
                                               int M, int N, int K) {
  __shared__ float Xs[64][17];
  __shared__ float Ws[64][17];
  int bm = blockIdx.y * 64, bn = blockIdx.x * 64;
  int tid = threadIdx.x;
  int tx = tid % 16, ty = tid / 16;
  float acc[4][4] = {};
  for (int k0 = 0; k0 < K; k0 += 16) {
    for (int i = tid; i < 64 * 16; i += 256) {
      int m = i / 16, k = i % 16;
      int gm = bm + m, gk = k0 + k, gn = bn + m;
      Xs[m][k] = (gm < M && gk < K) ? X[(size_t)gm * K + gk] : 0.f;
      Ws[m][k] = (gn < N && gk < K) ? W[(size_t)gn * K + gk] : 0.f;
    }
    __syncthreads();
    #pragma unroll
    for (int k = 0; k < 16; ++k) {
      float xv[4], wv[4];
      #pragma unroll
      for (int i = 0; i < 4; ++i) xv[i] = Xs[ty * 4 + i][k];
      #pragma unroll
      for (int j = 0; j < 4; ++j) wv[j] = Ws[tx * 4 + j][k];
      #pragma unroll
      for (int i = 0; i < 4; ++i)
        #pragma unroll
        for (int j = 0; j < 4; ++j) acc[i][j] += xv[i] * wv[j];
    }
    __syncthreads();
  }
  for (int i = 0; i < 4; ++i) {
    int gm = bm + ty * 4 + i;
    if (gm >= M) continue;
    for (int j = 0; j < 4; ++j) {
      int gn = bn + tx * 4 + j;
      if (gn >= N) continue;
      C[(size_t)gm * N + gn] = acc[i][j] + bias[gn];
    }
  }
}

// ---------------- persistent GRU scan: one launch per layer, fwd+bwd ----------------
// fwd blocks sync among themselves, bwd among themselves (independent groups).
__global__ __launch_bounds__(512, 1) void gru_scan_persist(
    const float* __restrict__ gxF, const float* __restrict__ gxB,
    const float* __restrict__ WhhF, const float* __restrict__ WhhB,
    const float* __restrict__ bhhF, const float* __restrict__ bhhB,
    float* __restrict__ hFA, float* __restrict__ hFB,
    float* __restrict__ hBA, float* __restrict__ hBB,
    float* __restrict__ yF, float* __restrict__ yB, int ystride,
    int* barF, int* barB) {
  __shared__ float w_lds[30 * 500];   // 60 KB
  __shared__ float gates[32];
  int dir = blockIdx.x / SB;
  int bu  = blockIdx.x % SB;
  int u0  = bu * UPB;
  const float* gx  = dir ? gxB : gxF;
  const float* Whh = dir ? WhhB : WhhF;
  const float* bhh = dir ? bhhB : bhhF;
  float* hA = dir ? hBA : hFA;
  float* hB = dir ? hBB : hFB;
  float* y  = dir ? yB : yF;
  int* bcnt = dir ? barB : barF;
  int* bgen = bcnt + 32;               // separate cacheline from cnt
  int tid = threadIdx.x, lane = tid & 63, wid = tid >> 6;

  // stage this block's Whh rows into LDS
  for (int idx = tid; idx < 30 * 500; idx += 512) {
    int r = idx / 500, k = idx - r * 500;
    int g = r / UPB, lu = r - g * UPB;
    w_lds[idx] = Whh[(size_t)(g * 500 + u0 + lu) * 500 + k];
  }
  __syncthreads();

  float hreg[8];
  for (int t = 0; t < SEQ; ++t) {
    const float* hin  = (t & 1) ? hB : hA;
    float*       hout = (t & 1) ? hA : hB;
    int teff = dir ? (SEQ - 1 - t) : t;
    #pragma unroll
    for (int j = 0; j < 8; ++j) {
      int k = lane + 64 * j;
      hreg[j] = (t > 0 && k < 500) ? gload(&hin[k]) : 0.f;
    }
    for (int r = wid; r < 30; r += 8) {
      const float* wr = &w_lds[r * 500];
      float acc = 0.f;
      #pragma unroll
      for (int j = 0; j < 8; ++j) {
        int k = lane + 64 * j;
        if (k < 500) acc += wr[k] * hreg[j];
      }
      acc = wred(acc);
      if (lane == 0) gates[r] = acc;
    }
    __syncthreads();
    if (tid < UPB) {
      int u = u0 + tid;
      float hold = (t > 0) ? gload(&hin[u]) : 0.f;
      const float* g = gx + (size_t)teff * H3;
      float rr = sigmoidf_(g[u]        + gates[tid]           + bhh[u]);
      float zz = sigmoidf_(g[500 + u]  + gates[UPB + tid]     + bhh[500 + u]);
      float nn = tanhf(    g[1000 + u] + rr * (gates[2 * UPB + tid] + bhh[1000 + u]));
      float hp = (1.f - zz) * nn + zz * hold;
      gstore(&hout[u], hp);
      y[(size_t)teff * ystride + u] = hp;
    }
    if (t < SEQ - 1) gbar(bcnt, bgen, SB);
  }
}

// ---------------- enc_out = y1f + y1b ----------------
__global__ void add_k(const float* __restrict__ a, const float* __restrict__ b,
                      float* __restrict__ c, int n) {
  int i = blockIdx.x * blockDim.x + threadIdx.x;
  if (i < n) c[i] = a[i] + b[i];
}

// ---------------- fused decoder step (cells + attention + concat) ----------------
__device__ __forceinline__ void cell_phase(int blk, int wid, int lane, int tid,
    const float* x_lds, const float* h_lds, float* gates,
    const float* Wih, const float* Whh, const float* bih, const float* bhh,
    float* hout) {
  for (int rr = wid; rr < 96; rr += 16) {
    int lu = rr & 15, kind = rr >> 4;
    int u = blk * 16 + lu;
    if (u < 500) {
      const float* row = (kind < 3) ? (Wih + (size_t)(kind * 500 + u) * 500)
                                    : (Whh + (size_t)((kind - 3) * 500 + u) * 500);
      const float* vec = (kind < 3) ? x_lds : h_lds;
      float acc = 0.f;
      #pragma unroll
      for (int j = 0; j < 8; ++j) {
        int k = lane + 64 * j;
        if (k < 500) acc += row[k] * vec[k];
      }
      acc = wred(acc);
      if (lane == 0) gates[rr] = acc;
    }
  }
  __syncthreads();
  if (tid < 16) {
    int u = blk * 16 + tid;
    if (u < 500) {
      float sxr = gates[tid],      sxz = gates[16 + tid], sxn = gates[32 + tid];
      float shr = gates[48 + tid], shz = gates[64 + tid], shn = gates[80 + tid];
      float r = sigmoidf_(sxr + bih[u]        + shr + bhh[u]);
      float z = sigmoidf_(sxz + bih[500 + u]  + shz + bhh[500 + u]);
      float n = tanhf(    sxn + bih[1000 + u] + r * (shn + bhh[1000 + u]));
      gstore(&hout[u], (1.f - z) * n + z * h_lds[u]);
    }
  }
}

__global__ __launch_bounds__(1024, 1) void dec_step_fused(
    const int* __restrict__ tok, const float* __restrict__ emb,
    const float* __restrict__ h0in, float* __restrict__ h0out,
    const float* __restrict__ h1in, float* __restrict__ h1out,
    const float* __restrict__ dWih, const float* __restrict__ dWhh,
    const float* __restrict__ dbih, const float* __restrict__ dbhh,
    const float* __restrict__ enc_out, const float* __restrict__ cW,
    const float* __restrict__ cb,
    float* __restrict__ scores, float* __restrict__ ctx, float* __restrict__ cvec,
    int* bcnt) {
  __shared__ float x_lds[512], h_lds[512], gates[96], red[256], sc_lds[256];
  int* bgen = bcnt + 32;
  int tid = threadIdx.x, lane = tid & 63, wid = tid >> 6, blk = blockIdx.x;

  // ---- phase A: layer-0 GRU cell (x = emb[tok]) ----
  int tk = tok[0];
  for (int i = tid; i < 500; i += 1024) {
    x_lds[i] = emb[(size_t)tk * 500 + i];
    h_lds[i] = h0in[i];
  }
  __syncthreads();
  cell_phase(blk, wid, lane, tid, x_lds, h_lds, gates, dWih, dWhh, dbih, dbhh, h0out);
  gbar(bcnt, bgen, 32);

  // ---- phase B: layer-1 GRU cell (x = h0out) ----
  for (int i = tid; i < 500; i += 1024) {
    x_lds[i] = gload(&h0out[i]);
    h_lds[i] = h1in[i];
  }
  __syncthreads();
  cell_phase(blk, wid, lane, tid, x_lds, h_lds, gates,
             dWih + 750000, dWhh + 750000, dbih + 1500, dbhh + 1500, h1out);
  gbar(bcnt, bgen, 32);

  // ---- phase C: attention scores (rnn = h1out) ----
  for (int i = tid; i < 500; i += 1024) x_lds[i] = gload(&h1out[i]);
  __syncthreads();
  if (wid < 8) {
    int s = blk * 8 + wid;
    const float* row = enc_out + (size_t)s * 500;
    float acc = 0.f;
    #pragma unroll
    for (int j = 0; j < 8; ++j) {
      int k = lane + 64 * j;
      if (k < 500) acc += row[k] * x_lds[k];
    }
    acc = wred(acc);
    if (lane == 0) gstore(&scores[s], acc);
  }
  gbar(bcnt, bgen, 32);

  // ---- phase D: softmax (each block computes full softmax) + ctx slice ----
  float myv = 0.f;
  if (tid < 256) { myv = gload(&scores[tid]); red[tid] = myv; }
  __syncthreads();
  for (int s = 128; s > 0; s >>= 1) {
    if (tid < s) red[tid] = fmaxf(red[tid], red[tid + s]);
    __syncthreads();
  }
  float m = red[0]; __syncthreads();
  float e = 0.f;
  if (tid < 256) { e = expf(myv - m); red[tid] = e; }
  __syncthreads();
  for (int s = 128; s > 0; s >>= 1) {
    if (tid < s) red[tid] += red[tid + s];
    __syncthreads();
  }
  float inv = 1.f / red[0]; __syncthreads();
  if (tid < 256) sc_lds[tid] = e * inv;
  __syncthreads();
  {
    int j = blk * 16 + wid;
    if (j < 500) {
      float acc = 0.f;
      #pragma unroll
      for (int q = 0; q < 4; ++q) {
        int s = lane + 64 * q;
        acc += sc_lds[s] * enc_out[(size_t)s * 500 + j];
      }
      acc = wred(acc);
      if (lane == 0) gstore(&ctx[j], acc);
    }
  }
  gbar(bcnt, bgen, 32);

  // ---- phase E: cvec = tanh(concat_W @ [rnn; ctx] + concat_b) ----
  for (int i = tid; i < 500; i += 1024) h_lds[i] = gload(&ctx[i]);  // x_lds = rnn
  __syncthreads();
  {
    int i = blk * 16 + wid;
    if (i < 500) {
      const float* row = cW + (size_t)i * 1000;
      float acc = 0.f;
      #pragma unroll
      for (int j = 0; j < 16; ++j) {
        int k = lane + 64 * j;
        if (k < 1000) {
          float v = (k < 500) ? x_lds[k] : h_lds[k - 500];
          acc += row[k] * v;
        }
      }
      acc = wred(acc);
      if (lane == 0) cvec[i] = tanhf(acc + cb[i]);
    }
  }
}

// ---------------- logits = out_W @ c + out_b, per-block max/argmax ----------------
__global__ __launch_bounds__(1024) void logits_k(const float* __restrict__ outW,
                                                 const float* __restrict__ outb,
                                                 const float* __restrict__ cvec,
                                                 float* __restrict__ logits,
                                                 float* __restrict__ pmax,
                                                 int* __restrict__ pidx) {
  __shared__ float4 c4[125];
  __shared__ float lmax[16];
  __shared__ int   lidx[16];
  if (threadIdx.x < 125) c4[threadIdx.x] = ((const float4*)cvec)[threadIdx.x];
  __syncthreads();
  int wid = threadIdx.x >> 6, lane = threadIdx.x & 63;
  int gw = blockIdx.x * 16 + wid;
  float bm = -INFINITY; int bi = V;
  #pragma unroll
  for (int rr = 0; rr < 4; ++rr) {
    int row = gw * 4 + rr;
    if (row < V) {
      const float4* wrow = (const float4*)(outW + (size_t)row * 500);
      float acc = 0.f;
      #pragma unroll
      for (int q = 0; q < 2; ++q) {
        int k4 = lane + 64 * q;
        if (k4 < 125) {
          float4 w4 = wrow[k4]; float4 cc = c4[k4];
          acc += w4.x * cc.x + w4.y * cc.y + w4.z * cc.z + w4.w * cc.w;
        }
      }
      acc = wred(acc);
      if (lane == 0) {
        float l = acc + outb[row];
        logits[row] = l;
        if (l > bm) { bm = l; bi = row; }
      }
    }
  }
  if (lane == 0) { lmax[wid] = bm; lidx[wid] = bi; }
  __syncthreads();
  if (threadIdx.x == 0) {
    float m = -INFINITY; int ix = V;
    for (int wq = 0; wq < 16; ++wq) {
      if (lmax[wq] > m || (lmax[wq] == m && lidx[wq] < ix)) { m = lmax[wq]; ix = lidx[wq]; }
    }
    pmax[blockIdx.x] = m; pidx[blockIdx.x] = ix;
  }
}

// ---------------- global argmax + softmax + write outputs ----------------
__global__ __launch_bounds__(1024) void finalize_k(const float* __restrict__ pmax,
                                                   const int* __restrict__ pidx, int nblk,
                                                   float* __restrict__ logits,
                                                   int* __restrict__ tok,
                                                   float* __restrict__ out_tokens,
                                                   float* __restrict__ out_probs, int step) {
  __shared__ float rm[1024];
  __shared__ int   ri[1024];
  int tid = threadIdx.x;
  float m = -INFINITY; int ix = V;
  for (int b = tid; b < nblk; b += 1024) {
    float v = pmax[b]; int id = pidx[b];
    if (v > m || (v == m && id < ix)) { m = v; ix = id; }
  }
  rm[tid] = m; ri[tid] = ix; __syncthreads();
  for (int s = 512; s > 0; s >>= 1) {
    if (tid < s) {
      if (rm[tid + s] > rm[tid] || (rm[tid + s] == rm[tid] && ri[tid + s] < ri[tid])) {
        rm[tid] = rm[tid + s]; ri[tid] = ri[tid + s];
      }
    }
    __syncthreads();
  }
  float gmax = rm[0]; int gidx = ri[0];
  __syncthreads();
  if (tid == 0) { tok[0] = gidx; out_tokens[step] = (float)gidx; }
  float sum = 0.f;
  for (int v = tid; v < V; v += 1024) {
    float e = expf(logits[v] - gmax);
    logits[v] = e;
    sum += e;
  }
  rm[tid] = sum; __syncthreads();
  for (int s = 512; s > 0; s >>= 1) {
    if (tid < s) rm[tid] += rm[tid + s];
    __syncthreads();
  }
  float inv = 1.f / rm[0];
  for (int v = tid; v < V; v += 1024)
    out_probs[(size_t)step * V + v] = logits[v] * inv;
}

extern "C" void kernel_launch(void* const* d_in, const int* in_sizes, int n_in,
                              void* d_out, int out_size, void* d_ws, size_t ws_size,
                              hipStream_t stream) {
  const int*   seq   = (const int*)d_in[0];
  const float* emb   = (const float*)d_in[3];
  const float* e0f_Wih = (const float*)d_in[4];
  const float* e0f_Whh = (const float*)d_in[5];
  const float* e0f_bih = (const float*)d_in[6];
  const float* e0f_bhh = (const float*)d_in[7];
  const float* e0b_Wih = (const float*)d_in[8];
  const float* e0b_Whh = (const float*)d_in[9];
  const float* e0b_bih = (const float*)d_in[10];
  const float* e0b_bhh = (const float*)d_in[11];
  const float* e1f_Wih = (const float*)d_in[12];
  const float* e1f_Whh = (const float*)d_in[13];
  const float* e1f_bih = (const float*)d_in[14];
  const float* e1f_bhh = (const float*)d_in[15];
  const float* e1b_Wih = (const float*)d_in[16];
  const float* e1b_Whh = (const float*)d_in[17];
  const float* e1b_bih = (const float*)d_in[18];
  const float* e1b_bhh = (const float*)d_in[19];
  const float* dWih = (const float*)d_in[20];
  const float* dWhh = (const float*)d_in[21];
  const float* dbih = (const float*)d_in[22];
  const float* dbhh = (const float*)d_in[23];
  const float* cW   = (const float*)d_in[24];
  const float* cb   = (const float*)d_in[25];
  const float* outW = (const float*)d_in[26];
  const float* outb = (const float*)d_in[27];

  float* w = (float*)d_ws;
  float* ex      = w;                      // 128000
  float* x1      = ex + 128000;            // 256000
  float* gxf     = x1 + 256000;            // 384000
  float* gxb     = gxf + 384000;           // 384000
  float* y1f     = gxb + 384000;           // 128000
  float* y1b     = y1f + 128000;           // 128000
  float* enc_out = y1b + 128000;           // 128000
  float* hb      = enc_out + 128000;       // 8 x 512 h ping-pong buffers
  float* hL0FA = hb;          float* hL0FB = hb + 512;
  float* hL0BA = hb + 1024;   float* hL0BB = hb + 1536;
  float* hL1FA = hb + 2048;   float* hL1FB = hb + 2560;
  float* hL1BA = hb + 3072;   float* hL1BB = hb + 3584;
  float* dsc0   = hb + 4096;               // 512
  float* dsc1   = dsc0 + 512;              // 512
  float* scores = dsc1 + 512;              // 512
  float* ctx    = scores + 512;            // 512
  float* cvec   = ctx + 512;               // 512
  float* logits = cvec + 512;              // 50432
  float* pmax   = logits + 50432;          // 1024
  int*   pidx   = (int*)(pmax + 1024);     // 1024 ints
  int*   tokp   = pidx + 1024;             // a few ints
  int*   bar    = tokp + 64;               // barrier area: 3 groups x {cnt, gen+32}

  float* outf = (float*)d_out;

  // zero barrier counters (d_ws is re-poisoned before every call)
  hipMemsetAsync(bar, 0, 256 * sizeof(int), stream);

  init_k<<<1, 64, 0, stream>>>(tokp);
  embed_k<<<SEQ, 128, 0, stream>>>(seq, emb, ex);

  // encoder layer 0: gate-input GEMMs, then persistent scan (fwd+bwd in one launch)
  gemm_nt<<<dim3(24, 4), 256, 0, stream>>>(ex, e0f_Wih, e0f_bih, gxf, SEQ, H3, H);
  gemm_nt<<<dim3(24, 4), 256, 0, stream>>>(ex, e0b_Wih, e0b_bih, gxb, SEQ, H3, H);
  gru_scan_persist<<<2 * SB, 512, 0, stream>>>(gxf, gxb, e0f_Whh, e0b_Whh,
      e0f_bhh, e0b_bhh, hL0FA, hL0FB, hL0BA, hL0BB, x1, x1 + 500, 1000,
      bar + 0, bar + 64);

  // encoder layer 1
  gemm_nt<<<dim3(24, 4), 256, 0, stream>>>(x1, e1f_Wih, e1f_bih, gxf, SEQ, H3, 2 * H);
  gemm_nt<<<dim3(24, 4), 256, 0, stream>>>(x1, e1b_Wih, e1b_bih, gxb, SEQ, H3, 2 * H);
  gru_scan_persist<<<2 * SB, 512, 0, stream>>>(gxf, gxb, e1f_Whh, e1b_Whh,
      e1f_bhh, e1b_bhh, hL1FA, hL1FB, hL1BA, hL1BB, y1f, y1b, 500,
      bar + 0, bar + 64);
  add_k<<<(SEQ * H + 255) / 256, 256, 0, stream>>>(y1f, y1b, enc_out, SEQ * H);

  // decoder: h ping-pong
  float* h0c = hL0FA; float* h0a = dsc0;
  float* h1c = hL0BA; float* h1a = dsc1;
  for (int st = 0; st < TDEC; ++st) {
    dec_step_fused<<<32, 1024, 0, stream>>>(tokp, emb, h0c, h0a, h1c, h1a,
        dWih, dWhh, dbih, dbhh, enc_out, cW, cb, scores, ctx, cvec,
        bar + 128);
    float* t0 = h0c; h0c = h0a; h0a = t0;
    float* t1 = h1c; h1c = h1a; h1a = t1;
    logits_k<<<NLB, 1024, 0, stream>>>(outW, outb, cvec, logits, pmax, pidx);
    finalize_k<<<1, 1024, 0, stream>>>(pmax, pidx, NLB, logits, tokp,
        outf, outf + TDEC, st);
  }
}